// Round 4
// baseline (100.995 us; speedup 1.0000x reference)
//
#include <hip/hip_runtime.h>

// Problem constants (from reference setup_inputs).
#define BATCH  4
#define NQ     8192
#define NA     6890
#define NSPLIT 16            // anchor splits = waves per block
#define QPB    64            // queries per block = one wave width
#define GPW    54            // 8-anchor groups per wave
#define NAPAD  (NSPLIT*GPW*8)  // 6912 padded anchors
#define PADH   1.0e30f

// ---- precompute: packed[b][k] = (x, y, z, 0.5*(x^2+y^2+z^2)), padded ----
__global__ void precompute_kernel(const float* __restrict__ anchor,
                                  float4* __restrict__ packed) {
    const int i = blockIdx.x * blockDim.x + threadIdx.x;
    if (i >= BATCH * NAPAD) return;
    const int b = i / NAPAD, k = i - b * NAPAD;
    float4 o;
    if (k < NA) {
        const float* a = anchor + ((size_t)b * NA + k) * 3;
        const float x = a[0], y = a[1], z = a[2];
        o = make_float4(x, y, z, 0.5f * (x*x + y*y + z*z));
    } else {
        o = make_float4(0.f, 0.f, 0.f, PADH);
    }
    packed[i] = o;
}

// 8 anchors = 32 floats per group, kept in SGPRs (wave-uniform loads).
#define DECL_BUF(p) \
  float p##00,p##01,p##02,p##03,p##04,p##05,p##06,p##07, \
        p##08,p##09,p##10,p##11,p##12,p##13,p##14,p##15, \
        p##16,p##17,p##18,p##19,p##20,p##21,p##22,p##23, \
        p##24,p##25,p##26,p##27,p##28,p##29,p##30,p##31;

#define LOAD_BUF(p, sp) do { const float* _s = (const float*)(sp); \
  p##00=_s[0];  p##01=_s[1];  p##02=_s[2];  p##03=_s[3]; \
  p##04=_s[4];  p##05=_s[5];  p##06=_s[6];  p##07=_s[7]; \
  p##08=_s[8];  p##09=_s[9];  p##10=_s[10]; p##11=_s[11]; \
  p##12=_s[12]; p##13=_s[13]; p##14=_s[14]; p##15=_s[15]; \
  p##16=_s[16]; p##17=_s[17]; p##18=_s[18]; p##19=_s[19]; \
  p##20=_s[20]; p##21=_s[21]; p##22=_s[22]; p##23=_s[23]; \
  p##24=_s[24]; p##25=_s[25]; p##26=_s[26]; p##27=_s[27]; \
  p##28=_s[28]; p##29=_s[29]; p##30=_s[30]; p##31=_s[31]; } while(0)

// score = h - q.a  (monotone in d^2 per query); 4 VALU ops, <=1 SGPR read each.
#define SCORE(ax,ay,az,hh,dst) do { \
  const float _dot = fmaf((az), qz, fmaf((ay), qy, (ax) * qx)); \
  dst = (hh) - _dot; } while(0)

// 8 scores -> min3 tree -> group-id tracking (strict < keeps earliest group).
#define COMP_BUF(p, gid) do { \
  float _s0,_s1,_s2,_s3,_s4,_s5,_s6,_s7; \
  SCORE(p##00,p##01,p##02,p##03,_s0); \
  SCORE(p##04,p##05,p##06,p##07,_s1); \
  SCORE(p##08,p##09,p##10,p##11,_s2); \
  SCORE(p##12,p##13,p##14,p##15,_s3); \
  SCORE(p##16,p##17,p##18,p##19,_s4); \
  SCORE(p##20,p##21,p##22,p##23,_s5); \
  SCORE(p##24,p##25,p##26,p##27,_s6); \
  SCORE(p##28,p##29,p##30,p##31,_s7); \
  const float _mA = fminf(fminf(_s0,_s1),_s2); \
  const float _mB = fminf(fminf(_s3,_s4),_s5); \
  const float _mC = fminf(fminf(_s6,_s7),_mA); \
  const float _mg = fminf(_mB,_mC); \
  const bool _p = (_mg < best); \
  best = _p ? _mg : best; \
  bgid = _p ? (gid) : bgid; } while(0)

__global__ __launch_bounds__(NSPLIT * 64)
void collision_kernel(const float* __restrict__ query,
                      const float* __restrict__ anchor,
                      const float* __restrict__ normals,
                      const float4* __restrict__ packed,
                      float* __restrict__ out) {
    __shared__ float s_sc[NSPLIT][QPB];
    __shared__ int   s_gd[NSPLIT][QPB];

    const int lane = threadIdx.x & 63;
    // Force wave index into an SGPR so anchor loads are provably wave-uniform.
    const int wave = __builtin_amdgcn_readfirstlane((int)(threadIdx.x >> 6));
    const int blocksPerBatch = NQ / QPB;                  // 128
    const int b = blockIdx.x / blocksPerBatch;
    const int q = (blockIdx.x % blocksPerBatch) * QPB + lane;

    const float* qp = query + ((size_t)b * NQ + q) * 3;
    const float qx = qp[0], qy = qp[1], qz = qp[2];

    const float4* __restrict__ PK = packed + (size_t)b * NAPAD;
    // This wave's 54 groups, all uniform — no tail anywhere.
    const float4* __restrict__ P4 = PK + (size_t)wave * GPW * 8;
    const int gbase = wave * GPW;

    float best = PADH;   // pad sentinel can never strictly beat itself
    int   bgid = gbase;

    DECL_BUF(c) DECL_BUF(t)
    LOAD_BUF(c, P4);
    int g = 0;
    // Double-buffered: no register copies, 2 groups per trip. GPW is even.
    while (g + 2 < GPW) {
        LOAD_BUF(t, P4 + 8 * (g + 1));
        COMP_BUF(c, gbase + g);
        LOAD_BUF(c, P4 + 8 * (g + 2));
        COMP_BUF(t, gbase + g + 1);
        g += 2;
    }
    LOAD_BUF(t, P4 + 8 * (GPW - 1));
    COMP_BUF(c, gbase + GPW - 2);
    COMP_BUF(t, gbase + GPW - 1);

    s_sc[wave][lane] = best;
    s_gd[wave][lane] = bgid;
    __syncthreads();

    if (threadIdx.x < QPB) {
        float bs = s_sc[0][lane];
        int   bg = s_gd[0][lane];
        #pragma unroll
        for (int s = 1; s < NSPLIT; ++s) {
            const float v = s_sc[s][lane];
            const int   gi = s_gd[s][lane];
            if (v < bs) { bs = v; bg = gi; }   // ascending s: ties keep earliest
        }
        // Rescan winning group (8 anchors) to resolve exact index.
        const float4* G = PK + (size_t)bg * 8;
        float rb = PADH; int rj = 0;
        #pragma unroll
        for (int j = 0; j < 8; ++j) {
            const float4 a = G[j];
            float sc; SCORE(a.x, a.y, a.z, a.w, sc);
            if (sc < rb) { rb = sc; rj = j; }  // ascending j: first occurrence
        }
        const int bidx = bg * 8 + rj;          // guaranteed < NA (pads can't win)
        // Exact d2 / dot for the collision predicate.
        const float* ap = anchor + ((size_t)b * NA + bidx) * 3;
        const float* np = normals + ((size_t)b * NA + bidx) * 3;
        const float dx = qx - ap[0], dy = qy - ap[1], dz = qz - ap[2];
        const float d2  = fmaf(dz, dz, fmaf(dy, dy, dx * dx));
        const float dot = fmaf(dz, np[2], fmaf(dy, np[1], dx * np[0]));
        // dot * (l2 <= 0.5) < 0  <=>  dot < 0 && d2 <= 0.25
        const bool coll = (dot < 0.0f) && (d2 <= 0.25f);
        const unsigned long long m = __ballot(coll);
        if (lane == 0) atomicAdd(out + b, (float)__popcll(m));
    }
}

extern "C" void kernel_launch(void* const* d_in, const int* in_sizes, int n_in,
                              void* d_out, int out_size, void* d_ws, size_t ws_size,
                              hipStream_t stream) {
    const float* query   = (const float*)d_in[0];
    const float* anchor  = (const float*)d_in[1];
    const float* normals = (const float*)d_in[2];
    float* out = (float*)d_out;
    float4* packed = (float4*)d_ws;        // BATCH*NAPAD*16B = 442 KB

    // d_out is poisoned with 0xAA before every call — zero it (graph-safe).
    hipMemsetAsync(d_out, 0, (size_t)out_size * sizeof(float), stream);

    const int npre = BATCH * NAPAD;
    precompute_kernel<<<dim3((npre + 255) / 256), dim3(256), 0, stream>>>(anchor, packed);

    const int grid = BATCH * (NQ / QPB);   // 512 blocks x 1024 threads
    collision_kernel<<<dim3(grid), dim3(NSPLIT * 64), 0, stream>>>(
        query, anchor, normals, packed, out);
}